// Round 2
// baseline (3157.941 us; speedup 1.0000x reference)
//
#include <hip/hip_runtime.h>
#include <hip/hip_bf16.h>

#define N_ROWS 1048576
#define F 256
#define STATS_BLOCKS 1024
#define ROWS_PER_BLOCK (N_ROWS / STATS_BLOCKS)

typedef float f32x4 __attribute__((ext_vector_type(4)));
typedef short short8 __attribute__((ext_vector_type(8)));

// ---- bf16 helpers (round-half-up; lo term compensates residual) ----
__device__ __forceinline__ ushort f2bf(float f) {
    unsigned int u = __float_as_uint(f);
    return (ushort)((u + 0x8000u) >> 16);
}
__device__ __forceinline__ float bf2f(ushort h) {
    return __uint_as_float(((unsigned int)h) << 16);
}

// ============ K1: per-feature sum / sumsq over 1M rows ============
__global__ __launch_bounds__(256) void stats_kernel(const float* __restrict__ x,
                                                    float* __restrict__ sums,
                                                    float* __restrict__ sumsq) {
    const int t = threadIdx.x;
    const int fgrp = t & 63;   // which float4 of the row
    const int rgrp = t >> 6;   // row sub-group 0..3
    f32x4 s = {0.f, 0.f, 0.f, 0.f};
    f32x4 q = {0.f, 0.f, 0.f, 0.f};
    const size_t row0 = (size_t)blockIdx.x * ROWS_PER_BLOCK;
    for (int r = rgrp; r < ROWS_PER_BLOCK; r += 4) {
        f32x4 v = *(const f32x4*)(x + (row0 + r) * F + fgrp * 4);
        s += v;
        q += v * v;
    }
    __shared__ f32x4 ls[4][64];
    __shared__ f32x4 lq[4][64];
    ls[rgrp][fgrp] = s;
    lq[rgrp][fgrp] = q;
    __syncthreads();
    if (t < 64) {
        f32x4 S = ls[0][t] + ls[1][t] + ls[2][t] + ls[3][t];
        f32x4 Q = lq[0][t] + lq[1][t] + lq[2][t] + lq[3][t];
        #pragma unroll
        for (int j = 0; j < 4; j++) {
            atomicAdd(&sums[t * 4 + j], S[j]);
            atomicAdd(&sumsq[t * 4 + j], Q[j]);
        }
    }
}

// ============ K2: fold BN into W -> bf16 hi/lo W', bias c ============
__global__ __launch_bounds__(256) void prep_kernel(const float* __restrict__ sums,
                                                   const float* __restrict__ sumsq,
                                                   const float* __restrict__ gamma,
                                                   const float* __restrict__ beta,
                                                   const float* __restrict__ W,
                                                   ushort* __restrict__ Whi,
                                                   ushort* __restrict__ Wlo,
                                                   float* __restrict__ c) {
    const int t = threadIdx.x;
    __shared__ float sa[F];
    __shared__ float sb[F];
    const float invN = 1.0f / (float)N_ROWS;
    float mean = sums[t] * invN;
    float var  = sumsq[t] * invN - mean * mean;
    float af   = gamma[t] * rsqrtf(var + 1e-5f);
    sa[t] = af;
    sb[t] = beta[t] - mean * af;
    __syncthreads();
    // thread t == output row o; W row-major [o][f] == B^T fragment layout
    float acc = 0.f;
    for (int f = 0; f < F; f++) {
        float w = W[(size_t)t * F + f];
        acc = fmaf(sb[f], w, acc);
        float wp = w * sa[f];
        ushort hi = f2bf(wp);
        ushort lo = f2bf(wp - bf2f(hi));
        Whi[t * F + f] = hi;
        Wlo[t * F + f] = lo;
    }
    c[t] = acc;
}

// ============ K3: y = x @ W'^T + c, then ELU ============
// block = 32 rows x 256 cols; 4 waves, wave wn owns cols [wn*64, wn*64+64)
// per wave: 2 m-tiles x 4 n-tiles of 16x16, K = 256 in 8 steps of 32
__global__ __launch_bounds__(256) void gemm_kernel(const float* __restrict__ x,
                                                   const ushort* __restrict__ Whi,
                                                   const ushort* __restrict__ Wlo,
                                                   const float* __restrict__ c,
                                                   float* __restrict__ out) {
    const int lane = threadIdx.x & 63;
    const int wn = threadIdx.x >> 6;
    const int r = lane & 15;
    const int g = lane >> 4;
    const size_t row0 = (size_t)blockIdx.x * 32;

    f32x4 acc[2][4];
    #pragma unroll
    for (int m = 0; m < 2; m++)
        #pragma unroll
        for (int n = 0; n < 4; n++)
            acc[m][n] = (f32x4){0.f, 0.f, 0.f, 0.f};

    const float* xA  = x + (row0 + r) * F + g * 8;              // A: row=r(+16m), k=g*8+j
    const ushort* Bh = Whi + (wn * 64 + r) * F + g * 8;         // B: col=r(+16n), k=g*8+j
    const ushort* Bl = Wlo + (wn * 64 + r) * F + g * 8;

    #pragma unroll
    for (int ks = 0; ks < 8; ks++) {
        const int k0 = ks * 32;
        // ---- load + split A (2 m-tiles) ----
        short8 ah[2], al[2];
        #pragma unroll
        for (int m = 0; m < 2; m++) {
            const float* p = xA + (size_t)m * 16 * F + k0;
            f32x4 v0 = *(const f32x4*)p;
            f32x4 v1 = *(const f32x4*)(p + 4);
            #pragma unroll
            for (int j = 0; j < 4; j++) {
                float f0 = v0[j], f1 = v1[j];
                ushort h0 = f2bf(f0), h1 = f2bf(f1);
                ah[m][j]     = (short)h0;
                ah[m][j + 4] = (short)h1;
                al[m][j]     = (short)f2bf(f0 - bf2f(h0));
                al[m][j + 4] = (short)f2bf(f1 - bf2f(h1));
            }
        }
        // ---- load B (4 n-tiles, hi+lo) ----
        short8 bh[4], bl[4];
        #pragma unroll
        for (int n = 0; n < 4; n++) {
            bh[n] = *(const short8*)(Bh + n * 16 * F + k0);
            bl[n] = *(const short8*)(Bl + n * 16 * F + k0);
        }
        // ---- MFMA: hh + hl + lh ----
        #pragma unroll
        for (int m = 0; m < 2; m++) {
            #pragma unroll
            for (int n = 0; n < 4; n++) {
                acc[m][n] = __builtin_amdgcn_mfma_f32_16x16x32_bf16(ah[m], bh[n], acc[m][n], 0, 0, 0);
                acc[m][n] = __builtin_amdgcn_mfma_f32_16x16x32_bf16(ah[m], bl[n], acc[m][n], 0, 0, 0);
                acc[m][n] = __builtin_amdgcn_mfma_f32_16x16x32_bf16(al[m], bh[n], acc[m][n], 0, 0, 0);
            }
        }
    }

    // ---- epilogue: bias + ELU, store ----
    // C/D layout: col = lane&15, row = (lane>>4)*4 + j   [m89-verified]
    #pragma unroll
    for (int n = 0; n < 4; n++) {
        const int col = wn * 64 + n * 16 + r;
        const float bias = c[col];
        #pragma unroll
        for (int m = 0; m < 2; m++) {
            #pragma unroll
            for (int j = 0; j < 4; j++) {
                const size_t row = row0 + m * 16 + g * 4 + j;
                float y = acc[m][n][j] + bias;
                y = y > 0.f ? y : expm1f(y);
                out[row * F + col] = y;
            }
        }
    }
}

extern "C" void kernel_launch(void* const* d_in, const int* in_sizes, int n_in,
                              void* d_out, int out_size, void* d_ws, size_t ws_size,
                              hipStream_t stream) {
    const float* x     = (const float*)d_in[0];
    const float* gamma = (const float*)d_in[1];
    const float* beta  = (const float*)d_in[2];
    const float* W     = (const float*)d_in[3];
    float* out = (float*)d_out;

    char* ws = (char*)d_ws;
    float* sums  = (float*)ws;            // 256 f32
    float* sumsq = sums + 256;            // 256 f32
    float* cvec  = sums + 512;            // 256 f32
    ushort* Whi  = (ushort*)(ws + 4096);            // 128 KB
    ushort* Wlo  = (ushort*)(ws + 4096 + F * F * 2); // 128 KB

    hipMemsetAsync(sums, 0, 512 * sizeof(float), stream);
    stats_kernel<<<STATS_BLOCKS, 256, 0, stream>>>(x, sums, sumsq);
    prep_kernel<<<1, 256, 0, stream>>>(sums, sumsq, gamma, beta, W, Whi, Wlo, cvec);
    gemm_kernel<<<N_ROWS / 32, 256, 0, stream>>>(x, Whi, Wlo, cvec, out);
}